// Round 16
// baseline (23.889 us; speedup 1.0000x reference)
//
#include <hip/hip_runtime.h>
#include <math.h>

#define H_DIM 1024
#define N_DIM 64
#define REPS 5   // measurement build: body x5 so dispatch tops rocprof

typedef __attribute__((ext_vector_type(8))) _Float16 f16x8;
typedef __attribute__((ext_vector_type(16))) float f32x16;

__device__ __forceinline__ float2 cmul(float2 a, float2 b) {
    return make_float2(fmaf(a.x, b.x, -(a.y * b.y)),
                       fmaf(a.x, b.y,   a.y * b.x));
}

__device__ __forceinline__ unsigned pkh(float x, float y) {
    const __fp16 __attribute__((ext_vector_type(2))) v =
        __builtin_amdgcn_cvt_pkrtz(x, y);    // v_cvt_pkrtz_f16_f32: 1 instr
    return __builtin_bit_cast(unsigned, v);
}

// ---------------- 32x32 MFMA path (REPS-instrumented) ----------------

__global__ __launch_bounds__(256, 2) void dss_mfma32r(
    const float* __restrict__ log_dt,   // (H,2)
    const float* __restrict__ llnr,     // (N,)
    const float* __restrict__ limv,     // (N,)
    const float* __restrict__ W,        // (H,N,2)
    const int*   __restrict__ Lp,
    float* __restrict__ out)            // (L,H)
{
    __shared__ unsigned lds_raw[4 * 2 * 32 * 64];   // 65536 B

    const int tid  = threadIdx.x;
    const int w    = tid >> 6;
    const int lane = tid & 63;               // = n

    const int raw = blockIdx.x + (blockIdx.y << 8);
    const int r7 = raw & 7, q9 = raw >> 3;
    const int half  = q9 >> 5;
    const int htile = (r7 << 5) | (q9 & 31);

    const int L  = *Lp;
    const int l0 = half << 10;
    if (l0 >= L) return;

    const int h = htile * 4 + w;

    unsigned* Atab = lds_raw + w * (2 * 32 * 64);
    unsigned* Btab = Atab + 32 * 64;

    int lx[8];
    #pragma unroll
    for (int m = 0; m < 8; ++m) lx[m] = lane ^ (m << 2);

    const float lre = -__expf(llnr[lane]);
    const float lmi = limv[lane];
    const float den = fmaxf(fmaf(lre, lre, lmi * lmi), 1e-14f);
    const float rde = __builtin_amdgcn_rcpf(den);
    const float rr = lre * rde, ri = -lmi * rde;

    const float dt0 = __expf(log_dt[2 * h]);
    const float dt1 = __expf(log_dt[2 * h + 1]);
    const float a = dt0 * lre;
    const float b = dt1 * lmi;
    const float eA = __expf(a);
    const float snb = __sinf(b), csb = __cosf(b);
    const float2 s = make_float2(eA * csb, eA * snb);

    const float2 wc = ((const float2*)W)[(size_t)h * N_DIM + lane];
    const float2 em1 = make_float2(s.x - 1.0f, s.y);
    const float2 t  = make_float2(em1.x * rr - em1.y * ri,
                                  em1.x * ri + em1.y * rr);
    const float2 wk = make_float2(wc.x * t.x - wc.y * t.y,
                                  wc.x * t.y + wc.y * t.x);

    const float2 s2 = cmul(s, s), s4 = cmul(s2, s2), s8 = cmul(s4, s4);
    const float2 s16 = cmul(s8, s8), s24 = cmul(s16, s8);
    const float2 s32 = cmul(s16, s16), s64 = cmul(s32, s32);
    const float2 s128 = cmul(s64, s64), s256 = cmul(s128, s128);
    const float2 s512 = cmul(s256, s256), s768 = cmul(s512, s256);
    const float2 s1024 = cmul(s512, s512);

    const float2 w0 = half ? cmul(wk, s1024) : wk;

    const int row = lane & 31;
    const int hi  = lane >> 5;
    const unsigned rsw = (unsigned)((row & 7) << 2);
    const unsigned* Arow = Atab + row * 64;
    const unsigned* Brow = Btab + row * 64;
    const int r32 = lane & 31;
    float* scr = (float*)lds_raw;
    float4* out4 = (float4*)out;

    #pragma unroll 1
    for (int rep = 0; rep < REPS; ++rep) {
        // ---- B rows: s^r packed (Re, -Im) ----
        {
            float2 v0 = make_float2(1.0f, 0.0f), v1 = s8, v2 = s16, v3 = s24;
            Btab[ 0 * 64 + lx[0]] = pkh(v0.x, -v0.y);
            Btab[ 8 * 64 + lx[0]] = pkh(v1.x, -v1.y);
            Btab[16 * 64 + lx[0]] = pkh(v2.x, -v2.y);
            Btab[24 * 64 + lx[0]] = pkh(v3.x, -v3.y);
            #pragma unroll
            for (int k = 1; k < 8; ++k) {
                v0 = cmul(v0, s); v1 = cmul(v1, s);
                v2 = cmul(v2, s); v3 = cmul(v3, s);
                Btab[( 0 + k) * 64 + lx[k]] = pkh(v0.x, -v0.y);
                Btab[( 8 + k) * 64 + lx[k]] = pkh(v1.x, -v1.y);
                Btab[(16 + k) * 64 + lx[k]] = pkh(v2.x, -v2.y);
                Btab[(24 + k) * 64 + lx[k]] = pkh(v3.x, -v3.y);
            }
        }
        // ---- A rows: w0*s32^q packed (Re, Im) ----
        {
            float2 v0 = w0, v1 = cmul(w0, s256), v2 = cmul(w0, s512), v3 = cmul(w0, s768);
            Atab[ 0 * 64 + lx[0]] = pkh(v0.x, v0.y);
            Atab[ 8 * 64 + lx[0]] = pkh(v1.x, v1.y);
            Atab[16 * 64 + lx[0]] = pkh(v2.x, v2.y);
            Atab[24 * 64 + lx[0]] = pkh(v3.x, v3.y);
            #pragma unroll
            for (int k = 1; k < 8; ++k) {
                v0 = cmul(v0, s32); v1 = cmul(v1, s32);
                v2 = cmul(v2, s32); v3 = cmul(v3, s32);
                Atab[( 0 + k) * 64 + lx[k]] = pkh(v0.x, v0.y);
                Atab[( 8 + k) * 64 + lx[k]] = pkh(v1.x, v1.y);
                Atab[(16 + k) * 64 + lx[k]] = pkh(v2.x, v2.y);
                Atab[(24 + k) * 64 + lx[k]] = pkh(v3.x, v3.y);
            }
        }

        // ---- 8 MFMA, dual accumulator chains (4-deep each) ----
        f32x16 acc0 = {0.0f,0.0f,0.0f,0.0f,0.0f,0.0f,0.0f,0.0f,
                       0.0f,0.0f,0.0f,0.0f,0.0f,0.0f,0.0f,0.0f};
        f32x16 acc1 = acc0;
        #pragma unroll
        for (int c = 0; c < 4; ++c) {
            const unsigned o0 = (unsigned)(8 * (2 * c)     + 4 * hi) ^ rsw;
            const unsigned o1 = (unsigned)(8 * (2 * c + 1) + 4 * hi) ^ rsw;
            const f16x8 a0 = *(const f16x8*)&Arow[o0];
            const f16x8 b0 = *(const f16x8*)&Brow[o0];
            acc0 = __builtin_amdgcn_mfma_f32_32x32x16_f16(a0, b0, acc0, 0, 0, 0);
            const f16x8 a1 = *(const f16x8*)&Arow[o1];
            const f16x8 b1 = *(const f16x8*)&Brow[o1];
            acc1 = __builtin_amdgcn_mfma_f32_32x32x16_f16(a1, b1, acc1, 0, 0, 0);
        }
        const f32x16 acc = acc0 + acc1;

        // ---- C stage: regs -> LDS [1024 l][5] (aliased over tables) ----
        __syncthreads();
        #pragma unroll
        for (int reg = 0; reg < 16; ++reg) {
            const int q = (reg & 3) + 8 * (reg >> 2) + 4 * hi;
            scr[(32 * q + r32) * 5 + w] = acc[reg];
        }
        __syncthreads();

        // ---- epilogue stores ----
        #pragma unroll
        for (int i = 0; i < 4; ++i) {
            const int l = i * 256 + tid;
            const int gl = l0 + l;
            if (gl < L) {
                const float* p = &scr[l * 5];
                out4[(size_t)gl * (H_DIM / 4) + htile] =
                    make_float4(p[0], p[1], p[2], p[3]);
            }
        }
        __syncthreads();   // protect tables for next rep
    }
}

// ---------------- generic fallback (round-1 proven structure) ----------------

#define HT 64
#define CHUNK 16

__global__ __launch_bounds__(256) void dss_kernel_fb(
    const float* __restrict__ log_dt,
    const float* __restrict__ lam_log_neg_re,
    const float* __restrict__ lam_im,
    const float* __restrict__ W,
    const int*   __restrict__ Lp,
    float* __restrict__ out,
    int H, int N)
{
    __shared__ float4 params[N_DIM * HT];
    const int tid = threadIdx.x;
    const int h0 = blockIdx.x * HT;
    const int l0_blk = blockIdx.y * 64;
    const int L = *Lp;
    const float2* __restrict__ W2 = (const float2*)W;

    for (int flat = tid; flat < N * HT; flat += 256) {
        const int hl = flat & (HT - 1);
        const int n  = flat >> 6;
        const int h  = h0 + hl;
        const float dt0 = expf(log_dt[2 * h]);
        const float dt1 = expf(log_dt[2 * h + 1]);
        const float lre = -expf(lam_log_neg_re[n]);
        const float lmi = lam_im[n];
        const float a = dt0 * lre;
        const float b = dt1 * lmi;
        const float eA = expf(a);
        float sb, cb;
        sincosf(b, &sb, &cb);
        const float em1r = eA * cb - 1.0f;
        const float em1i = eA * sb;
        const float den = fmaxf(lre * lre + lmi * lmi, 1e-14f);
        const float rr =  lre / den;
        const float ri = -lmi / den;
        const float2 wc = W2[h * N + n];
        const float trm = em1r * rr - em1i * ri;
        const float tim = em1r * ri + em1i * rr;
        params[flat] = make_float4(a, b,
                                   wc.x * trm - wc.y * tim,
                                   wc.x * tim + wc.y * trm);
    }
    __syncthreads();

    const int hl = tid & (HT - 1);
    const int chunk = tid >> 6;
    const int l0 = l0_blk + chunk * CHUNK;
    if (l0 >= L) return;

    float acc[CHUNK];
    #pragma unroll
    for (int k = 0; k < CHUNK; ++k) acc[k] = 0.0f;

    const double TWO_PI  = 6.283185307179586476925286766559;
    const double INV_2PI = 0.15915494309189533576888376337251;

    for (int n = 0; n < N; ++n) {
        const float4 pp = params[n * HT + hl];
        const float a = pp.x, b = pp.y, wr = pp.z, wi = pp.w;
        double ph = (double)b * (double)l0;
        ph -= TWO_PI * rint(ph * INV_2PI);
        const float th = (float)ph;
        const float e0 = expf(a * (float)l0);
        float s0, c0;
        sincosf(th, &s0, &c0);
        float zr = e0 * c0;
        float zi = e0 * s0;
        const float eA = expf(a);
        float sb, cb;
        sincosf(b, &sb, &cb);
        const float str = eA * cb;
        const float sti = eA * sb;
        #pragma unroll
        for (int k = 0; k < CHUNK; ++k) {
            acc[k] = fmaf(wr, zr, fmaf(-wi, zi, acc[k]));
            const float nzr = zr * str - zi * sti;
            const float nzi = fmaf(zr, sti, zi * str);
            zr = nzr; zi = nzi;
        }
    }

    #pragma unroll
    for (int k = 0; k < CHUNK; ++k) {
        const int l = l0 + k;
        if (l < L) out[(size_t)l * H + h0 + hl] = acc[k];
    }
}

// ---------------- launch ----------------

extern "C" void kernel_launch(void* const* d_in, const int* in_sizes, int n_in,
                              void* d_out, int out_size, void* d_ws, size_t ws_size,
                              hipStream_t stream) {
    const float* log_dt = (const float*)d_in[0];
    const float* llnr   = (const float*)d_in[1];
    const float* lim    = (const float*)d_in[2];
    const float* W      = (const float*)d_in[3];
    const int*   Lp     = (const int*)d_in[4];

    const int H = in_sizes[0] / 2;
    const int N = in_sizes[1];
    const int L = out_size / (H > 0 ? H : 1);

    if (H == H_DIM && N == N_DIM && L <= 2048) {
        const int halves = (L + 1023) / 1024;
        dim3 grid(H_DIM / 4, halves);            // 256 x 2 = 512 blocks
        dss_mfma32r<<<grid, 256, 0, stream>>>(log_dt, llnr, lim, W, Lp, (float*)d_out);
    } else {
        dim3 grid((H + HT - 1) / HT, (L + 63) / 64);
        dss_kernel_fb<<<grid, 256, 0, stream>>>(log_dt, llnr, lim, W, Lp,
                                                (float*)d_out, H, N);
    }
}

// Round 17
// 12.734 us; speedup vs baseline: 1.8760x; 1.8760x over previous
//
#include <hip/hip_runtime.h>
#include <math.h>

#define H_DIM 1024
#define N_DIM 64

typedef __attribute__((ext_vector_type(8))) _Float16 f16x8;
typedef __attribute__((ext_vector_type(16))) float f32x16;

__device__ __forceinline__ float2 cmul(float2 a, float2 b) {
    return make_float2(fmaf(a.x, b.x, -(a.y * b.y)),
                       fmaf(a.x, b.y,   a.y * b.x));
}

__device__ __forceinline__ unsigned pkh(float x, float y) {
    const __fp16 __attribute__((ext_vector_type(2))) v =
        __builtin_amdgcn_cvt_pkrtz(x, y);    // v_cvt_pkrtz_f16_f32: 1 instr
    return __builtin_bit_cast(unsigned, v);
}

// ---------------- 32x32 MFMA path, quarter tiles ----------------
// Block: 4 h x 512 l (4 waves; wave w owns h = 4*htile + w, lane = n).
// l - l0 = 32q + r, q in [0,16). A[q] = wk*s^l0*s32^q (16 rows, 4 KB),
// B[r] = s^r (32 rows, 8 KB) -> 12 KB/wave, 48 KB/block, 3 blocks/CU,
// 12 waves/CU. MFMA A-frag rows 16-31 read defined garbage (next table);
// C rows >=16 live in regs 8-15, never stored (DCE).

__global__ __launch_bounds__(256, 3) void dss_mfma32q(
    const float* __restrict__ log_dt,   // (H,2)
    const float* __restrict__ llnr,     // (N,)
    const float* __restrict__ limv,     // (N,)
    const float* __restrict__ W,        // (H,N,2)
    const int*   __restrict__ Lp,
    float* __restrict__ out)            // (L,H)
{
    __shared__ unsigned lds_raw[4 * 48 * 64];   // 49152 B

    const int tid  = threadIdx.x;
    const int w    = tid >> 6;
    const int lane = tid & 63;               // = n

    // XCD swizzle: contiguous 32-htile (128 h) span per XCD
    int htile, quarter;
    if (gridDim.y == 4 && gridDim.x == 256) {
        const int raw = blockIdx.x + (blockIdx.y << 8);
        const int xcd = raw & 7, q10 = raw >> 3;
        htile   = (xcd << 5) | (q10 & 31);
        quarter = q10 >> 5;
    } else { htile = blockIdx.x; quarter = blockIdx.y; }

    const int L  = *Lp;
    const int l0 = quarter << 9;
    if (l0 >= L) return;                     // block-uniform

    const int h = htile * 4 + w;

    unsigned* Atab = lds_raw + w * (48 * 64);
    unsigned* Btab = Atab + 16 * 64;

    int lx[8];
    #pragma unroll
    for (int m = 0; m < 8; ++m) lx[m] = lane ^ (m << 2);

    const float lre = -__expf(llnr[lane]);
    const float lmi = limv[lane];
    const float den = fmaxf(fmaf(lre, lre, lmi * lmi), 1e-14f);
    const float rde = __builtin_amdgcn_rcpf(den);
    const float rr = lre * rde, ri = -lmi * rde;

    const float dt0 = __expf(log_dt[2 * h]);
    const float dt1 = __expf(log_dt[2 * h + 1]);
    const float a = dt0 * lre;
    const float b = dt1 * lmi;
    const float eA = __expf(a);
    const float snb = __sinf(b), csb = __cosf(b);
    const float2 s = make_float2(eA * csb, eA * snb);

    const float2 wc = ((const float2*)W)[(size_t)h * N_DIM + lane];
    const float2 em1 = make_float2(s.x - 1.0f, s.y);
    const float2 t  = make_float2(em1.x * rr - em1.y * ri,
                                  em1.x * ri + em1.y * rr);
    const float2 wk = make_float2(wc.x * t.x - wc.y * t.y,
                                  wc.x * t.y + wc.y * t.x);

    const float2 s2 = cmul(s, s), s4 = cmul(s2, s2), s8 = cmul(s4, s4);
    const float2 s16 = cmul(s8, s8), s24 = cmul(s16, s8);
    const float2 s32 = cmul(s16, s16), s64 = cmul(s32, s32);
    const float2 s128 = cmul(s64, s64), s256 = cmul(s128, s128);
    const float2 s384 = cmul(s256, s128), s512 = cmul(s256, s256);
    const float2 s1024 = cmul(s512, s512);

    // w0 = wk * s^(512*quarter)
    float2 w0 = wk;
    if (quarter & 1) w0 = cmul(w0, s512);
    if (quarter & 2) w0 = cmul(w0, s1024);

    // ---- B rows r=0..31: s^r packed (Re, -Im); rows {k,8+k,16+k,24+k} ----
    {
        float2 v0 = make_float2(1.0f, 0.0f), v1 = s8, v2 = s16, v3 = s24;
        Btab[ 0 * 64 + lx[0]] = pkh(v0.x, -v0.y);
        Btab[ 8 * 64 + lx[0]] = pkh(v1.x, -v1.y);
        Btab[16 * 64 + lx[0]] = pkh(v2.x, -v2.y);
        Btab[24 * 64 + lx[0]] = pkh(v3.x, -v3.y);
        #pragma unroll
        for (int k = 1; k < 8; ++k) {
            v0 = cmul(v0, s); v1 = cmul(v1, s);
            v2 = cmul(v2, s); v3 = cmul(v3, s);
            Btab[( 0 + k) * 64 + lx[k]] = pkh(v0.x, -v0.y);
            Btab[( 8 + k) * 64 + lx[k]] = pkh(v1.x, -v1.y);
            Btab[(16 + k) * 64 + lx[k]] = pkh(v2.x, -v2.y);
            Btab[(24 + k) * 64 + lx[k]] = pkh(v3.x, -v3.y);
        }
    }
    // ---- A rows q=0..15: w0*s32^q packed; rows {k,4+k,8+k,12+k}, k<4 ----
    // row&7 for {k, 4+k, 8+k, 12+k} = {k, 4+k, k, 4+k} -> lx[k], lx[4+k]
    {
        float2 v0 = w0, v1 = cmul(w0, s128), v2 = cmul(w0, s256), v3 = cmul(w0, s384);
        Atab[ 0 * 64 + lx[0]] = pkh(v0.x, v0.y);
        Atab[ 4 * 64 + lx[4]] = pkh(v1.x, v1.y);
        Atab[ 8 * 64 + lx[0]] = pkh(v2.x, v2.y);
        Atab[12 * 64 + lx[4]] = pkh(v3.x, v3.y);
        #pragma unroll
        for (int k = 1; k < 4; ++k) {
            v0 = cmul(v0, s32); v1 = cmul(v1, s32);
            v2 = cmul(v2, s32); v3 = cmul(v3, s32);
            Atab[( 0 + k) * 64 + lx[k]]     = pkh(v0.x, v0.y);
            Atab[( 4 + k) * 64 + lx[4 + k]] = pkh(v1.x, v1.y);
            Atab[( 8 + k) * 64 + lx[k]]     = pkh(v2.x, v2.y);
            Atab[(12 + k) * 64 + lx[4 + k]] = pkh(v3.x, v3.y);
        }
    }

    // ---- 8 MFMA, dual accumulator chains ----
    const int row = lane & 31;
    const int hi  = lane >> 5;
    const unsigned rsw = (unsigned)((row & 7) << 2);
    const unsigned* Arow = Atab + row * 64;   // rows >=16 read Btab: discarded
    const unsigned* Brow = Btab + row * 64;
    f32x16 acc0 = {0.0f,0.0f,0.0f,0.0f,0.0f,0.0f,0.0f,0.0f,
                   0.0f,0.0f,0.0f,0.0f,0.0f,0.0f,0.0f,0.0f};
    f32x16 acc1 = acc0;
    #pragma unroll
    for (int c = 0; c < 4; ++c) {
        const unsigned o0 = (unsigned)(8 * (2 * c)     + 4 * hi) ^ rsw;
        const unsigned o1 = (unsigned)(8 * (2 * c + 1) + 4 * hi) ^ rsw;
        const f16x8 a0 = *(const f16x8*)&Arow[o0];
        const f16x8 b0 = *(const f16x8*)&Brow[o0];
        acc0 = __builtin_amdgcn_mfma_f32_32x32x16_f16(a0, b0, acc0, 0, 0, 0);
        const f16x8 a1 = *(const f16x8*)&Arow[o1];
        const f16x8 b1 = *(const f16x8*)&Brow[o1];
        acc1 = __builtin_amdgcn_mfma_f32_32x32x16_f16(a1, b1, acc1, 0, 0, 0);
    }

    // ---- C stage: regs 0..7 (q<16) -> LDS [512 l][5] (aliased) ----
    __syncthreads();                         // all waves done reading tables
    float* scr = (float*)lds_raw;            // 512 x 5 floats = 10240 B
    const int r32 = lane & 31;
    #pragma unroll
    for (int reg = 0; reg < 8; ++reg) {
        const float v = acc0[reg] + acc1[reg];
        const int q = (reg & 3) + 8 * (reg >> 2) + 4 * hi;   // 0..15
        scr[(32 * q + r32) * 5 + w] = v;
    }
    __syncthreads();

    // ---- epilogue: float4 stores ----
    float4* out4 = (float4*)out;
    #pragma unroll
    for (int i = 0; i < 2; ++i) {
        const int l = i * 256 + tid;
        const int gl = l0 + l;
        if (gl < L) {
            const float* p = &scr[l * 5];
            out4[(size_t)gl * (H_DIM / 4) + htile] =
                make_float4(p[0], p[1], p[2], p[3]);
        }
    }
}

// ---------------- generic fallback (round-1 proven structure) ----------------

#define HT 64
#define CHUNK 16

__global__ __launch_bounds__(256) void dss_kernel_fb(
    const float* __restrict__ log_dt,
    const float* __restrict__ lam_log_neg_re,
    const float* __restrict__ lam_im,
    const float* __restrict__ W,
    const int*   __restrict__ Lp,
    float* __restrict__ out,
    int H, int N)
{
    __shared__ float4 params[N_DIM * HT];
    const int tid = threadIdx.x;
    const int h0 = blockIdx.x * HT;
    const int l0_blk = blockIdx.y * 64;
    const int L = *Lp;
    const float2* __restrict__ W2 = (const float2*)W;

    for (int flat = tid; flat < N * HT; flat += 256) {
        const int hl = flat & (HT - 1);
        const int n  = flat >> 6;
        const int h  = h0 + hl;
        const float dt0 = expf(log_dt[2 * h]);
        const float dt1 = expf(log_dt[2 * h + 1]);
        const float lre = -expf(lam_log_neg_re[n]);
        const float lmi = lam_im[n];
        const float a = dt0 * lre;
        const float b = dt1 * lmi;
        const float eA = expf(a);
        float sb, cb;
        sincosf(b, &sb, &cb);
        const float em1r = eA * cb - 1.0f;
        const float em1i = eA * sb;
        const float den = fmaxf(lre * lre + lmi * lmi, 1e-14f);
        const float rr =  lre / den;
        const float ri = -lmi / den;
        const float2 wc = W2[h * N + n];
        const float trm = em1r * rr - em1i * ri;
        const float tim = em1r * ri + em1i * rr;
        params[flat] = make_float4(a, b,
                                   wc.x * trm - wc.y * tim,
                                   wc.x * tim + wc.y * trm);
    }
    __syncthreads();

    const int hl = tid & (HT - 1);
    const int chunk = tid >> 6;
    const int l0 = l0_blk + chunk * CHUNK;
    if (l0 >= L) return;

    float acc[CHUNK];
    #pragma unroll
    for (int k = 0; k < CHUNK; ++k) acc[k] = 0.0f;

    const double TWO_PI  = 6.283185307179586476925286766559;
    const double INV_2PI = 0.15915494309189533576888376337251;

    for (int n = 0; n < N; ++n) {
        const float4 pp = params[n * HT + hl];
        const float a = pp.x, b = pp.y, wr = pp.z, wi = pp.w;
        double ph = (double)b * (double)l0;
        ph -= TWO_PI * rint(ph * INV_2PI);
        const float th = (float)ph;
        const float e0 = expf(a * (float)l0);
        float s0, c0;
        sincosf(th, &s0, &c0);
        float zr = e0 * c0;
        float zi = e0 * s0;
        const float eA = expf(a);
        float sb, cb;
        sincosf(b, &sb, &cb);
        const float str = eA * cb;
        const float sti = eA * sb;
        #pragma unroll
        for (int k = 0; k < CHUNK; ++k) {
            acc[k] = fmaf(wr, zr, fmaf(-wi, zi, acc[k]));
            const float nzr = zr * str - zi * sti;
            const float nzi = fmaf(zr, sti, zi * str);
            zr = nzr; zi = nzi;
        }
    }

    #pragma unroll
    for (int k = 0; k < CHUNK; ++k) {
        const int l = l0 + k;
        if (l < L) out[(size_t)l * H + h0 + hl] = acc[k];
    }
}

// ---------------- launch ----------------

extern "C" void kernel_launch(void* const* d_in, const int* in_sizes, int n_in,
                              void* d_out, int out_size, void* d_ws, size_t ws_size,
                              hipStream_t stream) {
    const float* log_dt = (const float*)d_in[0];
    const float* llnr   = (const float*)d_in[1];
    const float* lim    = (const float*)d_in[2];
    const float* W      = (const float*)d_in[3];
    const int*   Lp     = (const int*)d_in[4];

    const int H = in_sizes[0] / 2;
    const int N = in_sizes[1];
    const int L = out_size / (H > 0 ? H : 1);

    if (H == H_DIM && N == N_DIM && L <= 2048) {
        const int quarters = (L + 511) / 512;
        dim3 grid(H_DIM / 4, quarters);          // 256 x 4 = 1024 blocks
        dss_mfma32q<<<grid, 256, 0, stream>>>(log_dt, llnr, lim, W, Lp, (float*)d_out);
    } else {
        dim3 grid((H + HT - 1) / HT, (L + 63) / 64);
        dss_kernel_fb<<<grid, 256, 0, stream>>>(log_dt, llnr, lim, W, Lp,
                                                (float*)d_out, H, N);
    }
}

// Round 18
// 10.862 us; speedup vs baseline: 2.1994x; 1.1724x over previous
//
#include <hip/hip_runtime.h>
#include <math.h>

#define H_DIM 1024
#define N_DIM 64

typedef __attribute__((ext_vector_type(8))) _Float16 f16x8;
typedef __attribute__((ext_vector_type(16))) float f32x16;

__device__ __forceinline__ float2 cmul(float2 a, float2 b) {
    return make_float2(fmaf(a.x, b.x, -(a.y * b.y)),
                       fmaf(a.x, b.y,   a.y * b.x));
}

__device__ __forceinline__ unsigned pkh(float x, float y) {
    const __fp16 __attribute__((ext_vector_type(2))) v =
        __builtin_amdgcn_cvt_pkrtz(x, y);
    return __builtin_bit_cast(unsigned, v);
}

// ---------------- 32x32 MFMA path, wide blocks ----------------
// Block: 8 h x 1024 l (8 waves of 512 threads; wave w owns h = 8*htile + w,
// lane = n). Same per-wave 16 KB A/B tables and 8x mfma_32x32x16 as R14.
// 256 blocks = 1/CU, 8 waves/CU. Epilogue: [l][9] scr (odd stride:
// conflict-free writes), 32 B/l-row output granule.

__global__ __launch_bounds__(512, 1) void dss_mfma32w(
    const float* __restrict__ log_dt,   // (H,2)
    const float* __restrict__ llnr,     // (N,)
    const float* __restrict__ limv,     // (N,)
    const float* __restrict__ W,        // (H,N,2)
    const int*   __restrict__ Lp,
    float* __restrict__ out)            // (L,H)
{
    __shared__ unsigned lds_raw[8 * 2 * 32 * 64];   // 131072 B

    const int tid  = threadIdx.x;
    const int w    = tid >> 6;               // 0..7
    const int lane = tid & 63;               // = n

    // XCD swizzle: 16 contiguous htiles (128 h) per XCD, same half
    int htile, half;
    if (gridDim.y == 2 && gridDim.x == 128) {
        const int raw = blockIdx.x + (blockIdx.y << 7);
        const int xcd = raw & 7, q = raw >> 3;      // q in [0,32)
        htile = (xcd << 4) | (q & 15);
        half  = q >> 4;
    } else { htile = blockIdx.x; half = blockIdx.y; }

    const int L  = *Lp;
    const int l0 = half << 10;
    if (l0 >= L) return;                     // block-uniform

    const int h = htile * 8 + w;

    unsigned* Atab = lds_raw + w * (2 * 32 * 64);
    unsigned* Btab = Atab + 32 * 64;

    int lx[8];
    #pragma unroll
    for (int m = 0; m < 8; ++m) lx[m] = lane ^ (m << 2);

    const float lre = -__expf(llnr[lane]);
    const float lmi = limv[lane];
    const float den = fmaxf(fmaf(lre, lre, lmi * lmi), 1e-14f);
    const float rde = __builtin_amdgcn_rcpf(den);
    const float rr = lre * rde, ri = -lmi * rde;

    const float dt0 = __expf(log_dt[2 * h]);
    const float dt1 = __expf(log_dt[2 * h + 1]);
    const float a = dt0 * lre;
    const float b = dt1 * lmi;
    const float eA = __expf(a);
    const float snb = __sinf(b), csb = __cosf(b);
    const float2 s = make_float2(eA * csb, eA * snb);

    const float2 wc = ((const float2*)W)[(size_t)h * N_DIM + lane];
    const float2 em1 = make_float2(s.x - 1.0f, s.y);
    const float2 t  = make_float2(em1.x * rr - em1.y * ri,
                                  em1.x * ri + em1.y * rr);
    const float2 wk = make_float2(wc.x * t.x - wc.y * t.y,
                                  wc.x * t.y + wc.y * t.x);

    const float2 s2 = cmul(s, s), s4 = cmul(s2, s2), s8 = cmul(s4, s4);
    const float2 s16 = cmul(s8, s8), s24 = cmul(s16, s8);
    const float2 s32 = cmul(s16, s16), s64 = cmul(s32, s32);
    const float2 s128 = cmul(s64, s64), s256 = cmul(s128, s128);
    const float2 s512 = cmul(s256, s256), s768 = cmul(s512, s256);
    const float2 s1024 = cmul(s512, s512);

    const float2 w0 = half ? cmul(wk, s1024) : wk;

    // ---- B rows r=0..31: s^r packed (Re, -Im) ----
    {
        float2 v0 = make_float2(1.0f, 0.0f), v1 = s8, v2 = s16, v3 = s24;
        Btab[ 0 * 64 + lx[0]] = pkh(v0.x, -v0.y);
        Btab[ 8 * 64 + lx[0]] = pkh(v1.x, -v1.y);
        Btab[16 * 64 + lx[0]] = pkh(v2.x, -v2.y);
        Btab[24 * 64 + lx[0]] = pkh(v3.x, -v3.y);
        #pragma unroll
        for (int k = 1; k < 8; ++k) {
            v0 = cmul(v0, s); v1 = cmul(v1, s);
            v2 = cmul(v2, s); v3 = cmul(v3, s);
            Btab[( 0 + k) * 64 + lx[k]] = pkh(v0.x, -v0.y);
            Btab[( 8 + k) * 64 + lx[k]] = pkh(v1.x, -v1.y);
            Btab[(16 + k) * 64 + lx[k]] = pkh(v2.x, -v2.y);
            Btab[(24 + k) * 64 + lx[k]] = pkh(v3.x, -v3.y);
        }
    }
    // ---- A rows q=0..31: w0*s32^q packed (Re, Im) ----
    {
        float2 v0 = w0, v1 = cmul(w0, s256), v2 = cmul(w0, s512), v3 = cmul(w0, s768);
        Atab[ 0 * 64 + lx[0]] = pkh(v0.x, v0.y);
        Atab[ 8 * 64 + lx[0]] = pkh(v1.x, v1.y);
        Atab[16 * 64 + lx[0]] = pkh(v2.x, v2.y);
        Atab[24 * 64 + lx[0]] = pkh(v3.x, v3.y);
        #pragma unroll
        for (int k = 1; k < 8; ++k) {
            v0 = cmul(v0, s32); v1 = cmul(v1, s32);
            v2 = cmul(v2, s32); v3 = cmul(v3, s32);
            Atab[( 0 + k) * 64 + lx[k]] = pkh(v0.x, v0.y);
            Atab[( 8 + k) * 64 + lx[k]] = pkh(v1.x, v1.y);
            Atab[(16 + k) * 64 + lx[k]] = pkh(v2.x, v2.y);
            Atab[(24 + k) * 64 + lx[k]] = pkh(v3.x, v3.y);
        }
    }

    // ---- 8 MFMA, dual accumulator chains ----
    const int row = lane & 31;
    const int hi  = lane >> 5;
    const unsigned rsw = (unsigned)((row & 7) << 2);
    const unsigned* Arow = Atab + row * 64;
    const unsigned* Brow = Btab + row * 64;
    f32x16 acc0 = {0.0f,0.0f,0.0f,0.0f,0.0f,0.0f,0.0f,0.0f,
                   0.0f,0.0f,0.0f,0.0f,0.0f,0.0f,0.0f,0.0f};
    f32x16 acc1 = acc0;
    #pragma unroll
    for (int c = 0; c < 4; ++c) {
        const unsigned o0 = (unsigned)(8 * (2 * c)     + 4 * hi) ^ rsw;
        const unsigned o1 = (unsigned)(8 * (2 * c + 1) + 4 * hi) ^ rsw;
        const f16x8 a0 = *(const f16x8*)&Arow[o0];
        const f16x8 b0 = *(const f16x8*)&Brow[o0];
        acc0 = __builtin_amdgcn_mfma_f32_32x32x16_f16(a0, b0, acc0, 0, 0, 0);
        const f16x8 a1 = *(const f16x8*)&Arow[o1];
        const f16x8 b1 = *(const f16x8*)&Brow[o1];
        acc1 = __builtin_amdgcn_mfma_f32_32x32x16_f16(a1, b1, acc1, 0, 0, 0);
    }

    // ---- C stage: regs -> LDS [1024 l][9] (odd stride: conflict-free) ----
    __syncthreads();                         // all waves done reading tables
    float* scr = (float*)lds_raw;            // 1024 x 9 floats = 36864 B
    const int r32 = lane & 31;
    #pragma unroll
    for (int reg = 0; reg < 16; ++reg) {
        const int q = (reg & 3) + 8 * (reg >> 2) + 4 * hi;
        scr[(32 * q + r32) * 9 + w] = acc0[reg] + acc1[reg];
    }
    __syncthreads();

    // ---- epilogue: 32 B per l-row (2 float4 quads) ----
    float4* out4 = (float4*)out;
    #pragma unroll
    for (int i = 0; i < 4; ++i) {
        const int flat = i * 512 + tid;      // 2048 = 1024 l x 2 quads
        const int l = flat >> 1, qq = flat & 1;
        const int gl = l0 + l;
        if (gl < L) {
            const float* p = &scr[l * 9 + 4 * qq];
            out4[(size_t)gl * (H_DIM / 4) + htile * 2 + qq] =
                make_float4(p[0], p[1], p[2], p[3]);
        }
    }
}

// ---------------- generic fallback (round-1 proven structure) ----------------

#define HT 64
#define CHUNK 16

__global__ __launch_bounds__(256) void dss_kernel_fb(
    const float* __restrict__ log_dt,
    const float* __restrict__ lam_log_neg_re,
    const float* __restrict__ lam_im,
    const float* __restrict__ W,
    const int*   __restrict__ Lp,
    float* __restrict__ out,
    int H, int N)
{
    __shared__ float4 params[N_DIM * HT];
    const int tid = threadIdx.x;
    const int h0 = blockIdx.x * HT;
    const int l0_blk = blockIdx.y * 64;
    const int L = *Lp;
    const float2* __restrict__ W2 = (const float2*)W;

    for (int flat = tid; flat < N * HT; flat += 256) {
        const int hl = flat & (HT - 1);
        const int n  = flat >> 6;
        const int h  = h0 + hl;
        const float dt0 = expf(log_dt[2 * h]);
        const float dt1 = expf(log_dt[2 * h + 1]);
        const float lre = -expf(lam_log_neg_re[n]);
        const float lmi = lam_im[n];
        const float a = dt0 * lre;
        const float b = dt1 * lmi;
        const float eA = expf(a);
        float sb, cb;
        sincosf(b, &sb, &cb);
        const float em1r = eA * cb - 1.0f;
        const float em1i = eA * sb;
        const float den = fmaxf(lre * lre + lmi * lmi, 1e-14f);
        const float rr =  lre / den;
        const float ri = -lmi / den;
        const float2 wc = W2[h * N + n];
        const float trm = em1r * rr - em1i * ri;
        const float tim = em1r * ri + em1i * rr;
        params[flat] = make_float4(a, b,
                                   wc.x * trm - wc.y * tim,
                                   wc.x * tim + wc.y * trm);
    }
    __syncthreads();

    const int hl = tid & (HT - 1);
    const int chunk = tid >> 6;
    const int l0 = l0_blk + chunk * CHUNK;
    if (l0 >= L) return;

    float acc[CHUNK];
    #pragma unroll
    for (int k = 0; k < CHUNK; ++k) acc[k] = 0.0f;

    const double TWO_PI  = 6.283185307179586476925286766559;
    const double INV_2PI = 0.15915494309189533576888376337251;

    for (int n = 0; n < N; ++n) {
        const float4 pp = params[n * HT + hl];
        const float a = pp.x, b = pp.y, wr = pp.z, wi = pp.w;
        double ph = (double)b * (double)l0;
        ph -= TWO_PI * rint(ph * INV_2PI);
        const float th = (float)ph;
        const float e0 = expf(a * (float)l0);
        float s0, c0;
        sincosf(th, &s0, &c0);
        float zr = e0 * c0;
        float zi = e0 * s0;
        const float eA = expf(a);
        float sb, cb;
        sincosf(b, &sb, &cb);
        const float str = eA * cb;
        const float sti = eA * sb;
        #pragma unroll
        for (int k = 0; k < CHUNK; ++k) {
            acc[k] = fmaf(wr, zr, fmaf(-wi, zi, acc[k]));
            const float nzr = zr * str - zi * sti;
            const float nzi = fmaf(zr, sti, zi * str);
            zr = nzr; zi = nzi;
        }
    }

    #pragma unroll
    for (int k = 0; k < CHUNK; ++k) {
        const int l = l0 + k;
        if (l < L) out[(size_t)l * H + h0 + hl] = acc[k];
    }
}

// ---------------- launch ----------------

extern "C" void kernel_launch(void* const* d_in, const int* in_sizes, int n_in,
                              void* d_out, int out_size, void* d_ws, size_t ws_size,
                              hipStream_t stream) {
    const float* log_dt = (const float*)d_in[0];
    const float* llnr   = (const float*)d_in[1];
    const float* lim    = (const float*)d_in[2];
    const float* W      = (const float*)d_in[3];
    const int*   Lp     = (const int*)d_in[4];

    const int H = in_sizes[0] / 2;
    const int N = in_sizes[1];
    const int L = out_size / (H > 0 ? H : 1);

    if (H == H_DIM && N == N_DIM && L <= 2048) {
        const int halves = (L + 1023) / 1024;
        dim3 grid(H_DIM / 8, halves);            // 128 x 2 = 256 blocks, 1/CU
        dss_mfma32w<<<grid, 512, 0, stream>>>(log_dt, llnr, lim, W, Lp, (float*)d_out);
    } else {
        dim3 grid((H + HT - 1) / HT, (L + 63) / 64);
        dss_kernel_fb<<<grid, 256, 0, stream>>>(log_dt, llnr, lim, W, Lp,
                                                (float*)d_out, H, N);
    }
}